// Round 15
// 646.285 us; speedup vs baseline: 2.6255x; 1.0021x over previous
//
#include <hip/hip_runtime.h>
#include <math.h>

#define KNN 75
#define NL 8
#define NB 1024
#define NT 50000
#define NT_PAD 50048  // NTB*TT rows allocated for bf16 banks (pad rows masked)
#define NCALI 10000
#define KC 32
#define TT 128
#define NTB 391       // ceil(NT/TT)
#define SLOTS 16      // per (q, t-block) slab: [count, up to 15 hit keys] = 64B
#define CAP 6144      // candidate buffer per query
#define NSUB 2048     // sampled train points for threshold
#define NSB 16        // NSUB/TT subset t-blocks
#define SSTRIDE 24
#define SOFF 11       // 11 + 24*2047 = 49139 < 50000
#define RSEL 32       // sample rank -> expected |{k < T}| ~ 780, lambda/slab ~ 2
#define MLP8_BQ 1563  // ceil(NT/32) bank blocks in mlp8 part; query blocks follow
#define MLPB (2*NTB+16)   // mlp_mfma grid: bank + 16 query blocks
#define ARENA 34816   // fused-kernel shared arena (final part is largest)

// prep_k block ranges
#define PB_Q    384                   // NB*96/256
#define PB_BANK 18750                 // NT*96/256
#define PB_W1   48                    // 128*96/256
#define PB_W23  64                    // 128*128/256
#define PREP_BLOCKS (PB_Q+PB_BANK+PB_W1+2*PB_W23)

typedef __attribute__((ext_vector_type(8))) short bf16x8;
typedef __attribute__((ext_vector_type(4))) float f32x4;

__device__ __forceinline__ int swz(int c){ return c + ((c>>5)<<2); }

__device__ __forceinline__ unsigned short f2bf_rn(float x){
  unsigned u = __float_as_uint(x);
  unsigned r = (u + 0x7FFFu + ((u>>16)&1u)) >> 16;
  return (unsigned short)r;
}
__device__ __forceinline__ float bf2f(unsigned short h){
  return __uint_as_float(((unsigned)h)<<16);
}
__device__ __forceinline__ bf16x8 ld8(const unsigned short* p){
  return *(const bf16x8*)p;
}
__device__ __forceinline__ void gl_lds16(const unsigned short* g, unsigned short* l){
  __builtin_amdgcn_global_load_lds(
      (const __attribute__((address_space(1))) void*)g,
      (__attribute__((address_space(3))) void*)l, 16, 0, 0);
}

// ---------------- fused prologue: pad copies + weight splits ------------------
__device__ __forceinline__ void pad_one(const float* __restrict__ in,
                                        float* __restrict__ out, int M,
                                        int Din, int Dout, int idx){
  if (idx >= M*Dout) return;
  int r = idx / Dout, c = idx - r*Dout;
  out[idx] = (c < Din) ? in[r*Din + c] : 0.f;
}
__device__ __forceinline__ void wsplit_one(const float* __restrict__ W, int kreal,
                                           int dp, unsigned short* __restrict__ WtH,
                                           unsigned short* __restrict__ WtL, int idx){
  int n = idx / dp, k = idx - n*dp;
  float v = (k < kreal) ? W[(size_t)k*128 + n] : 0.f;
  unsigned short h = f2bf_rn(v);
  WtH[idx] = h;
  WtL[idx] = f2bf_rn(v - bf2f(h));
}
__global__ void prep_k(const float* __restrict__ x, float* __restrict__ xq0,
                       const float* __restrict__ txr, float* __restrict__ tbA,
                       const float* __restrict__ W1, unsigned short* wt1H, unsigned short* wt1L,
                       const float* __restrict__ W2, unsigned short* wt2H, unsigned short* wt2L,
                       const float* __restrict__ W3, unsigned short* wt3H, unsigned short* wt3L){
  int b = blockIdx.x, tid = threadIdx.x;
  if (b < PB_Q){
    pad_one(x, xq0, NB, 83, 96, b*256 + tid);
  } else if (b < PB_Q + PB_BANK){
    pad_one(txr, tbA, NT, 83, 96, (b-PB_Q)*256 + tid);
  } else if (b < PB_Q + PB_BANK + PB_W1){
    wsplit_one(W1, 83, 96,  wt1H, wt1L, (b-PB_Q-PB_BANK)*256 + tid);
  } else if (b < PB_Q + PB_BANK + PB_W1 + PB_W23){
    wsplit_one(W2, 128, 128, wt2H, wt2L, (b-PB_Q-PB_BANK-PB_W1)*256 + tid);
  } else {
    wsplit_one(W3, 128, 128, wt3H, wt3L, (b-PB_Q-PB_BANK-PB_W1-PB_W23)*256 + tid);
  }
}

// ---- fp32 -> (hi,lo) bf16 split + row squared-norms (layer 0 only) -----------
__global__ void conv_norm_k(
    const float* __restrict__ XA, unsigned short* __restrict__ HA,
    unsigned short* __restrict__ LA, float* __restrict__ nA, int MA,
    const float* __restrict__ XB, unsigned short* __restrict__ HB,
    unsigned short* __restrict__ LB, float* __restrict__ nB, int MB,
    int dp)
{
  int w = threadIdx.x>>6, lane = threadIdx.x&63;
  int row = blockIdx.x*4 + w;
  const float* src; unsigned short* dh; unsigned short* dl; float* nrm;
  if (row < MA){
    src=&XA[(size_t)row*dp]; dh=&HA[(size_t)row*dp]; dl=&LA[(size_t)row*dp]; nrm=&nA[row];
  } else {
    int r2 = row - MA;
    if (r2 >= MB) return;
    src=&XB[(size_t)r2*dp]; dh=&HB[(size_t)r2*dp]; dl=&LB[(size_t)r2*dp]; nrm=&nB[r2];
  }
  float s=0.f;
  for (int c=lane*2; c<dp; c+=128){
    float2 v = *(const float2*)&src[c];
    s += v.x*v.x + v.y*v.y;
    unsigned short h0 = f2bf_rn(v.x), h1 = f2bf_rn(v.y);
    float r0 = v.x - bf2f(h0), r1 = v.y - bf2f(h1);
    ushort2 hh; hh.x=h0; hh.y=h1;
    ushort2 ll; ll.x=f2bf_rn(r0); ll.y=f2bf_rn(r1);
    *(ushort2*)&dh[c]=hh;
    *(ushort2*)&dl[c]=ll;
  }
  #pragma unroll
  for (int off=32;off>0;off>>=1) s += __shfl_down(s, off, 64);
  if (lane==0) *nrm=s;
}

// ---------------- scan helper: find bin containing rank Krem ------------------
__device__ __forceinline__ void find_bin(int* hist, int* part, int nb, int Krem,
                                         int tid, int* s_B, int* s_lob){
  int ch = nb>>8;
  int base = tid*ch;
  int s=0;
  for (int b=base;b<base+ch;b++) s+=hist[b];
  int lane = tid & 63, wv = tid>>6;
  int v = s;
  #pragma unroll
  for (int off=1; off<64; off<<=1){
    int u = __shfl_up(v, off, 64);
    if (lane >= off) v += u;
  }
  if (lane==63) part[wv] = v;
  __syncthreads();
  int wbase = 0;
  #pragma unroll
  for (int w2=0; w2<4; w2++) wbase += (w2 < wv) ? part[w2] : 0;
  v += wbase;
  int excl = v - s;
  if (v >= Krem && excl < Krem){
    int lob = excl, B = base + ch - 1;
    for (int b=base;b<base+ch;b++){
      if (lob + hist[b] >= Krem){ B=b; break; }
      lob += hist[b];
    }
    *s_B = B; *s_lob = lob;
  }
  if (tid==255 && v < Krem){ *s_B = nb-1; *s_lob = 0; }  // preserve old default
  __syncthreads();
}

// ---------------- per-query threshold: exact RSEL-th smallest sample key ------
__global__ __launch_bounds__(256) void sel64_k(const unsigned* __restrict__ skeys,
                                               unsigned* __restrict__ Tthr){
  __shared__ unsigned buf[NSUB];
  __shared__ int hist[2048];
  __shared__ int part[256];
  __shared__ int sB, sLob;
  int tid=threadIdx.x, q=blockIdx.x;
  for (int i=tid;i<NSUB;i+=256) buf[i]=skeys[(size_t)q*NSUB+i];
  int Krem=RSEL;
  for (int i=tid;i<2048;i+=256) hist[i]=0;
  __syncthreads();
  for (int i=tid;i<NSUB;i+=256) atomicAdd(&hist[buf[i]>>21],1);
  __syncthreads();
  find_bin(hist,part,2048,Krem,tid,&sB,&sLob);
  unsigned pre=(unsigned)sB; Krem-=sLob;
  for (int i=tid;i<2048;i+=256) hist[i]=0;
  __syncthreads();
  for (int i=tid;i<NSUB;i+=256){ unsigned k=buf[i]; if ((k>>21)==pre) atomicAdd(&hist[(k>>10)&0x7FFu],1); }
  __syncthreads();
  find_bin(hist,part,2048,Krem,tid,&sB,&sLob);
  pre=(pre<<11)|(unsigned)sB; Krem-=sLob;
  for (int i=tid;i<1024;i+=256) hist[i]=0;
  __syncthreads();
  for (int i=tid;i<NSUB;i+=256){ unsigned k=buf[i]; if ((k>>10)==pre) atomicAdd(&hist[k&0x3FFu],1); }
  __syncthreads();
  find_bin(hist,part,1024,Krem,tid,&sB,&sLob);
  if (tid==0) Tthr[q]=(pre<<10)|(unsigned)sB;
}

// ====== MFMA section: one 64x128 sub-tile x one K-chunk from LDS ==============
#define MFMA_SEC(BHC, BLC, AH, AL)                                               \
  _Pragma("unroll")                                                              \
  for (int tj=0;tj<8;tj++){                                                      \
    int rowB = tj*16 + col;                                                      \
    int sw = (((quad + (rowB>>1)) & 3) << 3);                                    \
    bf16x8 bh = *(const bf16x8*)&(BHC)[rowB*32 + sw];                            \
    bf16x8 bl = *(const bf16x8*)&(BLC)[rowB*32 + sw];                            \
    acc[tj] = __builtin_amdgcn_mfma_f32_16x16x32_bf16(AH, bh, acc[tj], 0,0,0);   \
    acc[tj] = __builtin_amdgcn_mfma_f32_16x16x32_bf16(AH, bl, acc[tj], 0,0,0);   \
    acc[tj] = __builtin_amdgcn_mfma_f32_16x16x32_bf16(AL, bh, acc[tj], 0,0,0);   \
  }

#define MFMA_KLOOP(ROWMAP)                                                       \
  size_t aoff = (size_t)(qbase + w*16 + col)*dp + quad*8;                        \
  const unsigned short* pAH = QH + aoff;                                         \
  const unsigned short* pAL = QL + aoff;                                         \
  int i0 = tid,      row0 = i0>>2, sg0 = ((i0&3) - (row0>>1)) & 3;               \
  int i1 = tid+256,  row1 = i1>>2, sg1 = ((i1&3) - (row1>>1)) & 3;               \
  size_t g0 = (size_t)(ROWMAP(n0+row0))*dp + (size_t)sg0*8;                      \
  size_t g1 = (size_t)(ROWMAP(n0+row1))*dp + (size_t)sg1*8;                      \
  f32x4 acc[8];                                                                  \
  _Pragma("unroll")                                                              \
  for (int tj=0;tj<8;tj++){ f32x4 z={0.f,0.f,0.f,0.f}; acc[tj]=z; }              \
  gl_lds16(TH + g0, BH0 + i0*8);                                                 \
  gl_lds16(TH + g1, BH0 + i1*8);                                                 \
  gl_lds16(TL + g0, BL0 + i0*8);                                                 \
  gl_lds16(TL + g1, BL0 + i1*8);                                                 \
  bf16x8 xh = ld8(pAH), xl = ld8(pAL);                                           \
  bf16x8 yh = xh, yl = xl;                                                       \
  _Pragma("unroll")                                                              \
  for (int kc=0; kc<kchunks; kc+=2){                                             \
    __syncthreads();                                                             \
    if (kc+1 < kchunks){                                                         \
      size_t ko=(size_t)(kc+1)*32;                                               \
      gl_lds16(TH + g0 + ko, BH1 + i0*8);                                        \
      gl_lds16(TH + g1 + ko, BH1 + i1*8);                                        \
      gl_lds16(TL + g0 + ko, BL1 + i0*8);                                        \
      gl_lds16(TL + g1 + ko, BL1 + i1*8);                                        \
      yh = ld8(pAH + ko); yl = ld8(pAL + ko);                                    \
    }                                                                            \
    MFMA_SEC(BH0, BL0, xh, xl);                                                  \
    if (kc+1 < kchunks){                                                         \
      __syncthreads();                                                           \
      if (kc+2 < kchunks){                                                       \
        size_t ko=(size_t)(kc+2)*32;                                             \
        gl_lds16(TH + g0 + ko, BH0 + i0*8);                                      \
        gl_lds16(TH + g1 + ko, BH0 + i1*8);                                      \
        gl_lds16(TL + g0 + ko, BL0 + i0*8);                                      \
        gl_lds16(TL + g1 + ko, BL0 + i1*8);                                      \
        xh = ld8(pAH + ko); xl = ld8(pAL + ko);                                  \
      }                                                                          \
      MFMA_SEC(BH1, BL1, yh, yl);                                                \
    }                                                                            \
  }

#define ROW_ID(r) (r)
#define ROW_SUB(r) ((r)*SSTRIDE + SOFF)

// ---------------- MFMA split-bf16 distance GEMM vs full bank (standalone) -----
template<int KCH>
__global__ __launch_bounds__(256) void dist_mfma_k(
    const unsigned short* __restrict__ QH, const unsigned short* __restrict__ QL,
    const unsigned short* __restrict__ TH, const unsigned short* __restrict__ TL,
    const float* __restrict__ qn, const float* __restrict__ tn,
    const int* __restrict__ labels, const unsigned* __restrict__ Tthr,
    unsigned* __restrict__ slab)
{
  constexpr int dp = KCH*32;
  __shared__ __align__(16) unsigned short smem[4*4096];   // 32 KB
  unsigned short* BH0 = smem;
  unsigned short* BH1 = smem + 4096;
  unsigned short* BL0 = smem + 8192;
  unsigned short* BL1 = smem + 12288;
  unsigned (*hitbuf)[SLOTS] = (unsigned (*)[SLOTS])smem;  // aliases BH0 (4 KB)
  int* hcnt = (int*)(smem + 4096);                        // aliases BH1 head
  int b = blockIdx.x;
  int xcd = b & 7, s = b >> 3;
  int qb = s & 15, tslot = s >> 4;
  int t_blk = xcd + 8*tslot;
  if (t_blk >= NTB) return;
  int tid = threadIdx.x, w = tid>>6, lane = tid&63;
  int quad = lane>>4, col = lane&15;
  int qbase = qb*64;
  int n0 = t_blk*TT;
  constexpr int kchunks = KCH;

  MFMA_KLOOP(ROW_ID)

  __syncthreads();
  if (tid<64) hcnt[tid]=0;
  __syncthreads();
  float qnr[4]; unsigned Tq[4]; float thrF[4];
  #pragma unroll
  for (int r=0;r<4;r++){
    int q = qbase + w*16 + quad*4 + r;
    qnr[r]  = qn[q];
    Tq[r]   = Tthr[q];
    thrF[r] = __uint_as_float(Tq[r] | 7u);  // superset boundary
  }
  #pragma unroll
  for (int tj=0;tj<8;tj++){
    int t = n0 + tj*16 + col;
    if (t < NT){
      float tnv = tn[t];
      unsigned lab = (unsigned)labels[t];
      #pragma unroll
      for (int r=0;r<4;r++){
        float d2 = fmaf(-2.f, acc[tj][r], qnr[r] + tnv);
        if (d2 <= thrF[r]){
          float d2c = fmaxf(d2, 0.f);
          unsigned key = (__float_as_uint(d2c)&0xFFFFFFF8u) | lab;
          if (key < Tq[r]){
            int ql = w*16 + quad*4 + r;
            int idx = atomicAdd(&hcnt[ql], 1);
            if (idx < SLOTS-1) hitbuf[ql][1+idx] = key;
          }
        }
      }
    }
  }
  __syncthreads();
  if (tid<64) hitbuf[tid][0]=(unsigned)hcnt[tid];
  __syncthreads();
  {
    int q = tid>>2, sub = (tid&3)*4;
    uint4 v = *(uint4*)&hitbuf[q][sub];
    *(uint4*)&slab[((size_t)(qbase+q)*NTB + t_blk)*SLOTS + sub] = v;
  }
}

// ---------------- dist_sub body (sampled subset distances) --------------------
template<int KCH>
__device__ __forceinline__ void distsub_body(char* smc, int b,
    const unsigned short* __restrict__ QH, const unsigned short* __restrict__ QL,
    const unsigned short* __restrict__ TH, const unsigned short* __restrict__ TL,
    const float* __restrict__ qn, const float* __restrict__ tn,
    const int* __restrict__ labels, unsigned* __restrict__ keys)
{
  constexpr int dp = KCH*32;
  unsigned short* BH0 = (unsigned short*)smc;
  unsigned short* BH1 = BH0 + 4096;
  unsigned short* BL0 = BH0 + 8192;
  unsigned short* BL1 = BH0 + 12288;
  int qb = b & 15, t_blk = b >> 4;           // t_blk in [0, NSB)
  int tid = threadIdx.x, w = tid>>6, lane = tid&63;
  int quad = lane>>4, col = lane&15;
  int qbase = qb*64;
  int n0 = t_blk*TT;
  constexpr int kchunks = KCH;

  MFMA_KLOOP(ROW_SUB)

  float qnr[4];
  #pragma unroll
  for (int r=0;r<4;r++)
    qnr[r] = qn[qbase + w*16 + quad*4 + r];
  #pragma unroll
  for (int tj=0;tj<8;tj++){
    int sI = n0 + tj*16 + col;
    int g  = sI*SSTRIDE + SOFF;
    float tnv = tn[g];
    unsigned lab = (unsigned)labels[g];
    #pragma unroll
    for (int r=0;r<4;r++){
      float d2 = fmaxf(fmaf(-2.f, acc[tj][r], qnr[r] + tnv), 0.f);
      unsigned key = (__float_as_uint(d2)&0xFFFFFFF8u) | lab;
      int q = qbase + w*16 + quad*4 + r;
      keys[(size_t)q*NSUB + sI] = key;
    }
  }
}

// ---------------- mlp body (bank rows; query rows for b >= 2*NTB) -------------
template<int KCH>
__device__ __forceinline__ void mlp_body(char* smc, int b,
    const unsigned short* __restrict__ bkH, const unsigned short* __restrict__ bkL,
    const unsigned short* __restrict__ qh,  const unsigned short* __restrict__ ql,
    const unsigned short* __restrict__ TH, const unsigned short* __restrict__ TL,
    const float* __restrict__ bias,
    float* __restrict__ OutB, unsigned short* __restrict__ SBH,
    unsigned short* __restrict__ SBL, float* __restrict__ nrmB,
    float* __restrict__ OutQ, unsigned short* __restrict__ SQH,
    unsigned short* __restrict__ SQL, float* __restrict__ nrmQ)
{
  constexpr int dp = KCH*32;
  unsigned short* BH0 = (unsigned short*)smc;
  unsigned short* BH1 = BH0 + 4096;
  unsigned short* BL0 = BH0 + 8192;
  unsigned short* BL1 = BH0 + 12288;
  bool isq = (b >= 2*NTB);
  const unsigned short* QH = isq ? qh : bkH;
  const unsigned short* QL = isq ? ql : bkL;
  float* Out = isq ? OutQ : OutB;
  unsigned short* SH = isq ? SQH : SBH;
  unsigned short* SL = isq ? SQL : SBL;
  float* nrm = isq ? nrmQ : nrmB;
  int M = isq ? NB : NT;
  int tid = threadIdx.x, w = tid>>6, lane = tid&63;
  int quad = lane>>4, col = lane&15;
  int qbase = (isq ? (b - 2*NTB) : b) * 64;
  int n0 = 0;
  constexpr int kchunks = KCH;

  MFMA_KLOOP(ROW_ID)

  float bb[8];
  #pragma unroll
  for (int tj=0;tj<8;tj++) bb[tj] = bias[tj*16 + col];
  #pragma unroll
  for (int r=0;r<4;r++){
    int row = qbase + w*16 + quad*4 + r;
    if (row < M){
      float vv[8]; float s=0.f;
      #pragma unroll
      for (int tj=0;tj<8;tj++){
        float v = acc[tj][r] + bb[tj];
        v = v > 0.f ? v : 0.f;
        vv[tj] = v;
        s += v*v;
        Out[(size_t)row*128 + tj*16 + col] = v;
      }
      #pragma unroll
      for (int off=1; off<16; off<<=1) s += __shfl_xor(s, off, 16);
      if (col==0) nrm[row] = s;
      #pragma unroll
      for (int tj=0;tj<8;tj++){
        unsigned short h = f2bf_rn(vv[tj]);
        SH[(size_t)row*128 + tj*16 + col] = h;
        SL[(size_t)row*128 + tj*16 + col] = f2bf_rn(vv[tj] - bf2f(h));
      }
    }
  }
}

// standalone mlp kernel (P2, P3 — ordered after the final that reads the fp32
// bank they overwrite, so they stay OUT of fused launches)
template<int KCH>
__global__ __launch_bounds__(256) void mlp_mfma_k(
    const unsigned short* bkH, const unsigned short* bkL,
    const unsigned short* qh,  const unsigned short* ql,
    const unsigned short* TH, const unsigned short* TL,
    const float* bias,
    float* OutB, unsigned short* SBH, unsigned short* SBL, float* nrmB,
    float* OutQ, unsigned short* SQH, unsigned short* SQL, float* nrmQ)
{
  __shared__ __align__(16) char smc[32768];
  mlp_body<KCH>(smc, blockIdx.x, bkH,bkL,qh,ql,TH,TL,bias,
                OutB,SBH,SBL,nrmB,OutQ,SQH,SQL,nrmQ);
}

// ---------------- mlp8 body: logits + softmax + split/norm --------------------
__device__ __forceinline__ void mlp8_body(char* smc, int b,
    const float* __restrict__ AB, const float* __restrict__ AQ,
    const float* __restrict__ W4, const float* __restrict__ b4,
    float* __restrict__ OutB, unsigned short* __restrict__ SBH,
    unsigned short* __restrict__ SBL, float* __restrict__ nrmB,
    float* __restrict__ OutQ, unsigned short* __restrict__ SQH,
    unsigned short* __restrict__ SQL, float* __restrict__ nrmQ)
{
  float* Ws = (float*)smc;
  int tid = threadIdx.x;
  for (int i=tid;i<1024;i+=256) Ws[i]=W4[i];
  __syncthreads();
  bool isq = (b >= MLP8_BQ);
  int r = (isq ? (b-MLP8_BQ) : b)*32 + (tid>>3), c = tid&7;
  int M = isq ? NB : NT;
  if (r >= M) return;
  const float* A = isq ? AQ : AB;
  float* Out = isq ? OutQ : OutB;
  unsigned short* SH = isq ? SQH : SBH;
  unsigned short* SL = isq ? SQL : SBL;
  float* nrm = isq ? nrmQ : nrmB;
  const float* a = &A[(size_t)r*128];
  float acc = b4[c];
  #pragma unroll 16
  for (int k=0;k<128;k++) acc += a[k]*Ws[k*8+c];
  int lane = tid & 63, base = lane & ~7;
  float v[8];
  #pragma unroll
  for (int j=0;j<8;j++) v[j] = __shfl(acc, base+j, 64);
  float m=-1e30f;
  #pragma unroll
  for (int j=0;j<8;j++) m = v[j]>m ? v[j] : m;
  float s=0.f;
  #pragma unroll
  for (int j=0;j<8;j++){ v[j]=__expf(v[j]-m); s+=v[j]; }
  float inv=1.f/s;
  float nn=0.f;
  #pragma unroll
  for (int j=0;j<8;j++){ float pv=v[j]*inv; v[j]=pv; nn+=pv*pv; }
  float* p = &Out[(size_t)r*32];
  float pv = v[c];
  p[c]    = pv;
  p[8+c]  = 0.f;
  p[16+c] = 0.f;
  p[24+c] = 0.f;
  unsigned short h = f2bf_rn(pv);
  SH[(size_t)r*32 + c]    = h;
  SL[(size_t)r*32 + c]    = f2bf_rn(pv - bf2f(h));
  SH[(size_t)r*32 + 8+c]  = 0; SL[(size_t)r*32 + 8+c]  = 0;
  SH[(size_t)r*32 + 16+c] = 0; SL[(size_t)r*32 + 16+c] = 0;
  SH[(size_t)r*32 + 24+c] = 0; SL[(size_t)r*32 + 24+c] = 0;
  if (c==0) nrm[r] = nn;
}

// ---------------- final body: gather slabs, radix select + class sums ---------
__device__ void final_body(char* sm, int q,
    const unsigned* __restrict__ slab,
    const float* __restrict__ Qm, const float* __restrict__ Tm,
    const float* __restrict__ qn, const float* __restrict__ tn,
    const int* __restrict__ labels,
    float* __restrict__ tot, int first, int dp)
{
  int* hist = (int*)sm;                         // 8192
  int* part = (int*)(sm+8192);                  // 1024
  unsigned* buf = (unsigned*)(sm+9216);         // 24576
  unsigned* lowbuf = (unsigned*)(sm+33792);     // 384
  float* qrow = (float*)(sm+34176);             // 512
  int* s_i = (int*)(sm+34688);                  // sB,sLob,s_cnt,s_low,s_bad
  float* s_w = (float*)(sm+34708);              // 9 floats
  int tid=threadIdx.x;
  if (tid==0){ for (int j=0;j<9;j++) s_w[j]=0.f; s_i[2]=0; s_i[3]=0; s_i[4]=0; }
  __syncthreads();

  const unsigned* sq = slab + (size_t)q*NTB*SLOTS;
  for (int sidx=tid; sidx<NTB; sidx+=256){
    const unsigned* s = sq + (size_t)sidx*SLOTS;
    uint4 a = *(const uint4*)s;
    unsigned cnt = a.x;
    if (cnt > SLOTS-1){ s_i[4]=1; continue; }
    if (!cnt) continue;
    int base = atomicAdd(&s_i[2], (int)cnt);
    if (base + (int)cnt <= CAP){
      buf[base] = a.y;
      if (cnt>=2) buf[base+1] = a.z;
      if (cnt>=3) buf[base+2] = a.w;
      for (unsigned w=4; w<=cnt; w++) buf[base+w-1] = s[w];
    }
  }
  __syncthreads();
  int total = s_i[2];
  int bad = s_i[4];

#define CONTRIB(kk) do{ float d2_=__uint_as_float((kk)&0xFFFFFFF8u); \
    if (d2_>0.f){ float w_=1.0f/sqrtf(d2_); \
      atomicAdd(&s_w[8],w_); atomicAdd(&s_w[(kk)&7u],w_); } }while(0)

  unsigned T; int Krem=KNN;
  if (!bad && total>=KNN && total<=CAP){
    for (int i=tid;i<2048;i+=256) hist[i]=0;
    __syncthreads();
    for (int i=tid;i<total;i+=256) atomicAdd(&hist[buf[i]>>21],1);
    __syncthreads();
    find_bin(hist,part,2048,Krem,tid,&s_i[0],&s_i[1]);
    unsigned pre=(unsigned)s_i[0]; Krem-=s_i[1];
    for (int i=tid;i<2048;i+=256) hist[i]=0;
    __syncthreads();
    for (int i=tid;i<total;i+=256){ unsigned k=buf[i]; if ((k>>21)==pre) atomicAdd(&hist[(k>>10)&0x7FFu],1); }
    __syncthreads();
    find_bin(hist,part,2048,Krem,tid,&s_i[0],&s_i[1]);
    pre=(pre<<11)|(unsigned)s_i[0]; Krem-=s_i[1];
    for (int i=tid;i<1024;i+=256) hist[i]=0;
    __syncthreads();
    for (int i=tid;i<total;i+=256){ unsigned k=buf[i]; if ((k>>10)==pre) atomicAdd(&hist[k&0x3FFu],1); }
    __syncthreads();
    find_bin(hist,part,1024,Krem,tid,&s_i[0],&s_i[1]);
    T=(pre<<10)|(unsigned)s_i[0]; Krem-=s_i[1];
    __syncthreads();
    for (int i=tid;i<total;i+=256){ unsigned k=buf[i]; if (k<T) CONTRIB(k); }
  } else {
    if (tid==0) s_i[2]=0;
    for (int i=tid;i<dp;i+=256) qrow[i]=Qm[(size_t)q*dp+i];
    __syncthreads();
    float qq=qn[q];
    auto KEY=[&](int t)->unsigned{
      const float* br=&Tm[(size_t)t*dp];
      float dot=0.f;
      for (int k2=0;k2<dp;k2++) dot+=qrow[k2]*br[k2];
      float d2=fmaxf(qq-2.f*dot+tn[t],0.f);
      return (__float_as_uint(d2)&0xFFFFFFF8u)|(unsigned)labels[t];
    };
    for (int i=tid;i<2048;i+=256) hist[i]=0;
    __syncthreads();
    for (int t=tid;t<NT;t+=256) atomicAdd(&hist[KEY(t)>>21],1);
    __syncthreads();
    find_bin(hist,part,2048,Krem,tid,&s_i[0],&s_i[1]);
    int c=hist[s_i[0]]; Krem-=s_i[1];
    unsigned prefix=(unsigned)s_i[0]; int shift=21;
    if (c > CAP){
      __syncthreads();
      for (int i=tid;i<2048;i+=256) hist[i]=0;
      __syncthreads();
      for (int t=tid;t<NT;t+=256){ unsigned k=KEY(t); if ((k>>21)==prefix) atomicAdd(&hist[(k>>10)&0x7FFu],1); }
      __syncthreads();
      find_bin(hist,part,2048,Krem,tid,&s_i[0],&s_i[1]);
      c=hist[s_i[0]]; Krem-=s_i[1]; prefix=(prefix<<11)|(unsigned)s_i[0]; shift=10;
    }
    if (c > CAP){
      __syncthreads();
      for (int i=tid;i<1024;i+=256) hist[i]=0;
      __syncthreads();
      for (int t=tid;t<NT;t+=256){ unsigned k=KEY(t); if ((k>>10)==prefix) atomicAdd(&hist[k&0x3FFu],1); }
      __syncthreads();
      find_bin(hist,part,1024,Krem,tid,&s_i[0],&s_i[1]);
      c=hist[s_i[0]]; Krem-=s_i[1]; prefix=(prefix<<10)|(unsigned)s_i[0]; shift=0;
    }
    if (c <= CAP){
      for (int t=tid;t<NT;t+=256){
        unsigned k=KEY(t); unsigned pp=k>>shift;
        if (pp==prefix){ int j=atomicAdd(&s_i[2],1); if (j<CAP) buf[j]=k; }
        else if (pp<prefix){ int j=atomicAdd(&s_i[3],1); if (j<96) lowbuf[j]=k; }
      }
      __syncthreads();
      int sh=shift;
      while (sh>0){
        int nsh=(sh==21)?10:0;
        int nb=1<<(sh-nsh);
        __syncthreads();
        for (int i=tid;i<nb;i+=256) hist[i]=0;
        __syncthreads();
        int cc=s_i[2];
        for (int i=tid;i<cc;i+=256) atomicAdd(&hist[(buf[i]>>nsh)&(unsigned)(nb-1)],1);
        __syncthreads();
        find_bin(hist,part,nb,Krem,tid,&s_i[0],&s_i[1]);
        Krem-=s_i[1]; prefix=(prefix<<(sh-nsh))|(unsigned)s_i[0]; sh=nsh;
      }
      T=prefix;
      __syncthreads();
      int lowc=s_i[3], cc=s_i[2];
      for (int i=tid;i<lowc;i+=256){ unsigned k=lowbuf[i]; CONTRIB(k); }
      for (int i=tid;i<cc;i+=256){ unsigned k=buf[i]; if (k<T) CONTRIB(k); }
    } else {
      T=prefix;
      for (int t=tid;t<NT;t+=256){ unsigned k=KEY(t); if (k<T) CONTRIB(k); }
    }
  }
  __syncthreads();
  if (tid==0){
    float d2=__uint_as_float(T&0xFFFFFFF8u);
    float w=(d2>0.f)?(1.0f/sqrtf(d2)):0.f;
    s_w[8] += (float)Krem*w;
    s_w[T&7u] += (float)Krem*w;
  }
  __syncthreads();
  if (tid<8){
    float contrib = s_w[8]-s_w[tid];
    size_t o=(size_t)q*NL+tid;
    tot[o] = first ? contrib : tot[o]+contrib;
  }
#undef CONTRIB
}

// standalone final (layer 4, no fusion partner)
__global__ __launch_bounds__(256) void final_k(
    const unsigned* slab, const float* Qm, const float* Tm,
    const float* qn, const float* tn, const int* labels,
    float* tot, int first, int dp)
{
  __shared__ __align__(16) char sm[ARENA];
  final_body(sm, blockIdx.x, slab, Qm, Tm, qn, tn, labels, tot, first, dp);
}

// ---------------- fused launch: [final nf][dist_sub 256][mlp | mlp8] ----------
// All parts mutually independent (disjoint buffers; verified against the
// per-layer buffer rotation). Branch is uniform per block -> barriers safe.
template<int KSUB, int KMLP, int M8>
__global__ __launch_bounds__(256) void fused_k(
    int nf,
    // final part
    const unsigned* slab, const float* Qm, const float* Tm,
    const float* qnF, const float* tnF, float* tot, int first, int dpF,
    // dist_sub part
    const unsigned short* qhS, const unsigned short* qlS,
    const unsigned short* bkHS, const unsigned short* bkLS,
    const float* qnS, const float* tnS, unsigned* skeys,
    const int* labels,
    // mlp part (KMLP>0)
    const unsigned short* bkHM, const unsigned short* bkLM,
    const unsigned short* qhM, const unsigned short* qlM,
    const unsigned short* wtH, const unsigned short* wtL, const float* bias,
    float* OutB, unsigned short* SBH, unsigned short* SBL, float* nrmB,
    float* OutQ, unsigned short* SQH, unsigned short* SQL, float* nrmQ,
    // mlp8 part (M8)
    const float* AB8, const float* AQ8, const float* W4, const float* b4)
{
  __shared__ __align__(16) char sm[ARENA];
  int b = blockIdx.x;
  if (b < nf){
    final_body(sm, b, slab, Qm, Tm, qnF, tnF, labels, tot, first, dpF);
    return;
  }
  b -= nf;
  if (b < 16*NSB){
    distsub_body<KSUB>(sm, b, qhS, qlS, bkHS, bkLS, qnS, tnS, labels, skeys);
    return;
  }
  b -= 16*NSB;
  if constexpr (KMLP > 0){
    mlp_body<KMLP>(sm, b, bkHM,bkLM,qhM,qlM, wtH,wtL, bias,   // FIX: weights as B
                   OutB,SBH,SBL,nrmB,OutQ,SQH,SQL,nrmQ);
  } else if constexpr (M8){
    mlp8_body(sm, b, AB8, AQ8, W4, b4, OutB,SBH,SBL,nrmB,OutQ,SQH,SQL,nrmQ);
  }
}

// ---------------- empirical p-values ------------------------------------------
__global__ void pvalue_k(const float* __restrict__ tot, const float* __restrict__ cali,
                         float* __restrict__ out){
  __shared__ float t8[NL];
  __shared__ int part[4][NL];
  int tid=threadIdx.x, q=blockIdx.x;
  if (tid<NL) t8[tid]=tot[(size_t)q*NL+tid];
  __syncthreads();
  float th[NL];
  #pragma unroll
  for (int c=0;c<NL;c++) th[c]=t8[c];
  int cnt[NL];
  #pragma unroll
  for (int c=0;c<NL;c++) cnt[c]=0;
  for (int i=tid;i<NCALI;i+=256){
    float v=cali[i];
    #pragma unroll
    for (int c=0;c<NL;c++) cnt[c] += (v>=th[c]) ? 1 : 0;
  }
  #pragma unroll
  for (int c=0;c<NL;c++){
    #pragma unroll
    for (int off=32;off>0;off>>=1) cnt[c]+=__shfl_down(cnt[c],off,64);
  }
  if ((tid&63)==0){
    #pragma unroll
    for (int c=0;c<NL;c++) part[tid>>6][c]=cnt[c];
  }
  __syncthreads();
  if (tid<NL){
    int s=part[0][tid]+part[1][tid]+part[2][tid]+part[3][tid];
    out[(size_t)q*NL+tid] = (float)s / 10000.f;
  }
}

extern "C" void kernel_launch(void* const* d_in, const int* in_sizes, int n_in,
                              void* d_out, int out_size, void* d_ws, size_t ws_size,
                              hipStream_t stream) {
  const float* x   = (const float*)d_in[0];
  const float* txr = (const float*)d_in[1];
  const int*   lbl = (const int*)  d_in[2];
  const float* cal = (const float*)d_in[3];
  const float* W1  = (const float*)d_in[4];
  const float* b1  = (const float*)d_in[5];
  const float* W2  = (const float*)d_in[6];
  const float* b2  = (const float*)d_in[7];
  const float* W3  = (const float*)d_in[8];
  const float* b3  = (const float*)d_in[9];
  const float* W4  = (const float*)d_in[10];
  const float* b4  = (const float*)d_in[11];
  float* out = (float*)d_out;
  float* ws  = (float*)d_ws;

  size_t off=0;
  float* xq0=ws+off; off+=(size_t)NB*96;
  float* xq1=ws+off; off+=(size_t)NB*128;
  float* xq2=ws+off; off+=(size_t)NB*128;
  float* xq3=ws+off; off+=(size_t)NB*128;
  float* xq4=ws+off; off+=(size_t)NB*32;
  float* tbA=ws+off; off+=(size_t)NT*128;
  float* tbB=ws+off; off+=(size_t)NT*128;
  float* tb4=ws+off; off+=(size_t)NT*32;
  float* qnb=ws+off; off+=(size_t)5*NB;
  float* tnb=ws+off; off+=(size_t)5*NT;     // per-layer norm slices
  float* tot=ws+off; off+=(size_t)NB*NL;
  unsigned* sT=(unsigned*)(ws+off); off+=NB;
  // per-layer query splits (hi/lo), strides: L0=96, L1-3=128, L4=32
  unsigned short* qH0=(unsigned short*)(ws+off); off+=(size_t)NB*48;
  unsigned short* qL0=(unsigned short*)(ws+off); off+=(size_t)NB*48;
  unsigned short* qH1=(unsigned short*)(ws+off); off+=(size_t)NB*64;
  unsigned short* qL1=(unsigned short*)(ws+off); off+=(size_t)NB*64;
  unsigned short* qH2=(unsigned short*)(ws+off); off+=(size_t)NB*64;
  unsigned short* qL2=(unsigned short*)(ws+off); off+=(size_t)NB*64;
  unsigned short* qH3=(unsigned short*)(ws+off); off+=(size_t)NB*64;
  unsigned short* qL3=(unsigned short*)(ws+off); off+=(size_t)NB*64;
  unsigned short* qH4=(unsigned short*)(ws+off); off+=(size_t)NB*16;
  unsigned short* qL4=(unsigned short*)(ws+off); off+=(size_t)NB*16;
  // double-buffered bank splits (producer writes the pair not being read)
  unsigned short* bkAH=(unsigned short*)(ws+off); off+=(size_t)NT_PAD*64;
  unsigned short* bkAL=(unsigned short*)(ws+off); off+=(size_t)NT_PAD*64;
  unsigned short* bkBH=(unsigned short*)(ws+off); off+=(size_t)NT_PAD*64;
  unsigned short* bkBL=(unsigned short*)(ws+off); off+=(size_t)NT_PAD*64;
  unsigned short* wt1H=(unsigned short*)(ws+off); off+=(size_t)128*48;
  unsigned short* wt1L=(unsigned short*)(ws+off); off+=(size_t)128*48;
  unsigned short* wt2H=(unsigned short*)(ws+off); off+=(size_t)128*64;
  unsigned short* wt2L=(unsigned short*)(ws+off); off+=(size_t)128*64;
  unsigned short* wt3H=(unsigned short*)(ws+off); off+=(size_t)128*64;
  unsigned short* wt3L=(unsigned short*)(ws+off); off+=(size_t)128*64;
  off=(off+3)&~(size_t)3;
  unsigned* slab=(unsigned*)(ws+off); off+=(size_t)NB*NTB*SLOTS;  // 25.6 MB
  unsigned* skeys=(unsigned*)(ws+off); off+=(size_t)NB*NSUB;      // de-aliased:
  // dist_sub(i+1) writes skeys while final(i) reads slab in the SAME launch.

  float* tnb0=tnb, *tnb1=tnb+NT, *tnb2=tnb+2*NT, *tnb3=tnb+3*NT, *tnb4=tnb+4*NT;

  prep_k<<<PREP_BLOCKS,256,0,stream>>>(x,xq0,txr,tbA,
                                       W1,wt1H,wt1L,W2,wt2H,wt2L,W3,wt3H,wt3L);
  conv_norm_k<<<(NT+NB)/4,256,0,stream>>>(tbA, bkAH, bkAL, tnb0, NT,
                                          xq0, qH0, qL0, qnb+0*NB, NB, 96);

  // A0: dist_sub(0) || P(1)=mlp<3> (L1 fp32->tbB, split->bkB, tnb1)
  fused_k<3,3,0><<<16*NSB + MLPB,256,0,stream>>>(0,
      nullptr,nullptr,nullptr,nullptr,nullptr,nullptr,0,0,
      qH0,qL0, bkAH,bkAL, qnb+0*NB, tnb0, skeys, lbl,
      bkAH,bkAL, qH0,qL0, wt1H,wt1L, b1,
      tbB,bkBH,bkBL,tnb1, xq1,qH1,qL1,qnb+1*NB,
      nullptr,nullptr,nullptr,nullptr);
  sel64_k<<<NB,256,0,stream>>>(skeys,sT);
  dist_mfma_k<3><<<8*16*49,256,0,stream>>>(qH0,qL0,bkAH,bkAL,qnb+0*NB,tnb0,lbl,sT,slab);

  // A1: final(0) || dist_sub(1)
  fused_k<4,0,0><<<NB + 16*NSB,256,0,stream>>>(NB,
      slab, xq0, tbA, qnb+0*NB, tnb0, tot, 1, 96,
      qH1,qL1, bkBH,bkBL, qnb+1*NB, tnb1, skeys, lbl,
      nullptr,nullptr,nullptr,nullptr,nullptr,nullptr,nullptr,
      nullptr,nullptr,nullptr,nullptr,nullptr,nullptr,nullptr,nullptr,
      nullptr,nullptr,nullptr,nullptr);
  // P(2): L2 fp32->tbA (final(0) already read tbA), split->bkA, tnb2
  mlp_mfma_k<4><<<MLPB,256,0,stream>>>(bkBH,bkBL, qH1,qL1, wt2H,wt2L, b2,
                                       tbA,bkAH,bkAL,tnb2, xq2,qH2,qL2,qnb+2*NB);
  sel64_k<<<NB,256,0,stream>>>(skeys,sT);
  dist_mfma_k<4><<<8*16*49,256,0,stream>>>(qH1,qL1,bkBH,bkBL,qnb+1*NB,tnb1,lbl,sT,slab);

  // A2: final(1) || dist_sub(2)
  fused_k<4,0,0><<<NB + 16*NSB,256,0,stream>>>(NB,
      slab, xq1, tbB, qnb+1*NB, tnb1, tot, 0, 128,
      qH2,qL2, bkAH,bkAL, qnb+2*NB, tnb2, skeys, lbl,
      nullptr,nullptr,nullptr,nullptr,nullptr,nullptr,nullptr,
      nullptr,nullptr,nullptr,nullptr,nullptr,nullptr,nullptr,nullptr,
      nullptr,nullptr,nullptr,nullptr);
  // P(3): L3 fp32->tbB (final(1) already read tbB), split->bkB, tnb3
  mlp_mfma_k<4><<<MLPB,256,0,stream>>>(bkAH,bkAL, qH2,qL2, wt3H,wt3L, b3,
                                       tbB,bkBH,bkBL,tnb3, xq3,qH3,qL3,qnb+3*NB);
  sel64_k<<<NB,256,0,stream>>>(skeys,sT);
  dist_mfma_k<4><<<8*16*49,256,0,stream>>>(qH2,qL2,bkAH,bkAL,qnb+2*NB,tnb2,lbl,sT,slab);

  // A3: final(2) || dist_sub(3) || P(4)=mlp8sm (reads tbB/xq3; writes tb4, bkA
  // split [L2 split readers all done], tnb4) — no conflict with final(2)@tbA.
  fused_k<4,0,1><<<NB + 16*NSB + MLP8_BQ+32,256,0,stream>>>(NB,
      slab, xq2, tbA, qnb+2*NB, tnb2, tot, 0, 128,
      qH3,qL3, bkBH,bkBL, qnb+3*NB, tnb3, skeys, lbl,
      nullptr,nullptr,nullptr,nullptr,nullptr,nullptr,nullptr,
      tb4,bkAH,bkAL,tnb4, xq4,qH4,qL4,qnb+4*NB,
      tbB, xq3, W4, b4);
  sel64_k<<<NB,256,0,stream>>>(skeys,sT);
  dist_mfma_k<4><<<8*16*49,256,0,stream>>>(qH3,qL3,bkBH,bkBL,qnb+3*NB,tnb3,lbl,sT,slab);

  // A4: final(3) || dist_sub(4)
  fused_k<1,0,0><<<NB + 16*NSB,256,0,stream>>>(NB,
      slab, xq3, tbB, qnb+3*NB, tnb3, tot, 0, 128,
      qH4,qL4, bkAH,bkAL, qnb+4*NB, tnb4, skeys, lbl,
      nullptr,nullptr,nullptr,nullptr,nullptr,nullptr,nullptr,
      nullptr,nullptr,nullptr,nullptr,nullptr,nullptr,nullptr,nullptr,
      nullptr,nullptr,nullptr,nullptr);
  sel64_k<<<NB,256,0,stream>>>(skeys,sT);
  dist_mfma_k<1><<<8*16*49,256,0,stream>>>(qH4,qL4,bkAH,bkAL,qnb+4*NB,tnb4,lbl,sT,slab);

  final_k<<<NB,256,0,stream>>>(slab, xq4, tb4, qnb+4*NB, tnb4, lbl, tot, 0, 32);

  pvalue_k<<<NB,256,0,stream>>>(tot,cal,out);
}